// Round 2
// baseline (333.110 us; speedup 1.0000x reference)
//
#include <hip/hip_runtime.h>

#define HH 128
#define WW 128
#define CIN 64
#define COUT 64
#define HW (HH * WW)

// -------------------------------------------------------------------------
// Kernel 1: offset conv. P=2 rows per thread, weights in LDS as [c][t][8]
// (padded row so each (c,t) weight sextet is two aligned float4 reads).
// Block: 4 rows x 128 cols (256 threads, thread = 1 col x 2 rows).
// -------------------------------------------------------------------------
__global__ __launch_bounds__(256) void offset_kernel(const float* __restrict__ x,
                                                     const float* __restrict__ ow,
                                                     const float* __restrict__ obias,
                                                     float* __restrict__ off) {
    __shared__ float lw[CIN * 9 * 8];   // 18 KB, [c][t][j pad 8]
    const int tid = threadIdx.x;
    for (int i = tid; i < CIN * 9 * 6; i += 256) {
        int j = i % 6;
        int t = (i / 6) % 9;
        int c = i / 54;
        lw[(c * 9 + t) * 8 + j] = ow[(j * CIN + c) * 9 + t];
    }
    __syncthreads();

    const int blk = blockIdx.x;              // b(8) x ytile(32)
    const int b   = blk >> 5;
    const int y0  = ((blk & 31) << 2) + ((tid >> 7) << 1);  // rows y0, y0+1
    const int col = tid & 127;

    const float* xb = x + (size_t)b * CIN * HW;

    float acc[2][6];
#pragma unroll
    for (int j = 0; j < 6; ++j) {
        float bj = obias[j];
        acc[0][j] = bj;
        acc[1][j] = bj;
    }

    for (int c = 0; c < CIN; ++c) {
        const float* xc = xb + c * HW;
        float rv[4][3];                      // rows y0-1..y0+2, cols col-1..col+1
#pragma unroll
        for (int r = 0; r < 4; ++r) {
            int yy = y0 - 1 + r;
            bool yv = (yy >= 0) && (yy < HH);
            int ycl = min(max(yy, 0), HH - 1);
#pragma unroll
            for (int d = 0; d < 3; ++d) {
                int xx = col - 1 + d;
                bool xv = (xx >= 0) && (xx < WW);
                int xcl = min(max(xx, 0), WW - 1);
                float val = xc[ycl * WW + xcl];
                rv[r][d] = (yv && xv) ? val : 0.f;
            }
        }
#pragma unroll
        for (int t = 0; t < 9; ++t) {
            int ty = t / 3, dx = t % 3;
            const float4* wp = (const float4*)&lw[(c * 9 + t) * 8];
            float4 wa = wp[0];
            float4 wb = wp[1];
            float w6[6] = {wa.x, wa.y, wa.z, wa.w, wb.x, wb.y};
#pragma unroll
            for (int p = 0; p < 2; ++p) {
                float v = rv[ty + p][dx];
#pragma unroll
                for (int j = 0; j < 6; ++j) acc[p][j] += v * w6[j];
            }
        }
    }
#pragma unroll
    for (int j = 0; j < 6; ++j)
#pragma unroll
        for (int p = 0; p < 2; ++p)
            off[((size_t)(b * 6 + j) * HH + (y0 + p)) * WW + col] = acc[p][j];
}

// -------------------------------------------------------------------------
// Kernel 2: deformable strip conv. Register blocking: thread = 4 pixel-rows
// x 16 outputs (64 accs). Block = 4 waves (one 16-out slice each) over a
// 4-row x 64-col pixel tile. Weight LDS reads amortized 4x vs round 1:
// per (tap, c) one wave does 4 ds_read_b128 feeding 256 FMAs.
// Gather loads stay NCHW lane-coalesced b32 (L2-friendly, FETCH was 134MB).
// -------------------------------------------------------------------------
__global__ __launch_bounds__(256) void main_kernel(const float* __restrict__ x,
                                                   const float* __restrict__ off,
                                                   const float* __restrict__ wh,
                                                   const float* __restrict__ wv,
                                                   float* __restrict__ out) {
    __shared__ float lw[3 * CIN * COUT];   // [k][c][o], 48 KB per phase

    const int tid   = threadIdx.x;
    const int lane  = tid & 63;
    const int wbase = (tid >> 6) << 4;     // this wave's 16-output slice

    const int blk = blockIdx.x;            // b(8) x ytile(32) x xtile(2)
    const int b   = blk >> 6;
    const int yt  = (blk >> 1) & 31;
    const int y0  = yt << 2;               // rows y0..y0+3
    const int col = ((blk & 1) << 6) + lane;

    const float* xb   = x   + (size_t)b * CIN * HW;
    const float* offb = off + (size_t)b * 6 * HW;

    float acc[4][16];
#pragma unroll
    for (int q = 0; q < 4; ++q)
#pragma unroll
        for (int o = 0; o < 16; ++o) acc[q][o] = 0.f;

#pragma unroll
    for (int phase = 0; phase < 2; ++phase) {
        const float* wsrc = phase ? wv : wh;
        __syncthreads();                   // protect previous phase's reads
        for (int i = tid; i < 3 * CIN * COUT; i += 256) {
            int o = i & 63;
            int c = (i >> 6) & 63;
            int k = i >> 12;
            lw[i] = wsrc[(o * CIN + c) * 3 + k];  // wh (O,C,1,K) / wv (O,C,K,1) flatten same
        }
        __syncthreads();

        for (int k = 0; k < 3; ++k) {
            float wA[4], wB[4];
            int idxA[4], idxB[4];
#pragma unroll
            for (int q = 0; q < 4; ++q) {
                int y = y0 + q;
                float o1 = offb[((phase * 3 + k) * HH + y) * WW + col];
                if (phase == 0) {
                    // horizontal: py = y + off (frac), px = col + k - 1 (int)
                    float py  = (float)y + o1;
                    float y0f = floorf(py);
                    float wy  = py - y0f;
                    int   yi  = (int)y0f;
                    bool v0 = (yi >= 0) && (yi <= HH - 1);
                    bool v1 = (yi + 1 >= 0) && (yi + 1 <= HH - 1);
                    int  px = col + k - 1;
                    bool pv = (px >= 0) && (px <= WW - 1);
                    wA[q] = (pv && v0) ? (1.f - wy) : 0.f;
                    wB[q] = (pv && v1) ? wy : 0.f;
                    int ra = min(max(yi, 0), HH - 1);
                    int rb = min(max(yi + 1, 0), HH - 1);
                    int ca = min(max(px, 0), WW - 1);
                    idxA[q] = ra * WW + ca;
                    idxB[q] = rb * WW + ca;
                } else {
                    // vertical: py = y + k - 1 (int), px = col + off (frac)
                    float px  = (float)col + o1;
                    float x0f = floorf(px);
                    float wx  = px - x0f;
                    int   xi  = (int)x0f;
                    bool v0 = (xi >= 0) && (xi <= WW - 1);
                    bool v1 = (xi + 1 >= 0) && (xi + 1 <= WW - 1);
                    int  py = y + k - 1;
                    bool pv = (py >= 0) && (py <= HH - 1);
                    wA[q] = (pv && v0) ? (1.f - wx) : 0.f;
                    wB[q] = (pv && v1) ? wx : 0.f;
                    int ra = min(max(py, 0), HH - 1);
                    int ca = min(max(xi, 0), WW - 1);
                    int cb = min(max(xi + 1, 0), WW - 1);
                    idxA[q] = ra * WW + ca;
                    idxB[q] = ra * WW + cb;
                }
            }

            for (int c = 0; c < CIN; ++c) {
                const float* xc = xb + c * HW;
                float v[4];
#pragma unroll
                for (int q = 0; q < 4; ++q)
                    v[q] = wA[q] * xc[idxA[q]] + wB[q] * xc[idxB[q]];

                const float4* wp = (const float4*)&lw[(k * CIN + c) * COUT + wbase];
                float4 w0 = wp[0];
                float4 w1 = wp[1];
                float4 w2 = wp[2];
                float4 w3 = wp[3];
#pragma unroll
                for (int q = 0; q < 4; ++q) {
                    acc[q][0]  += v[q] * w0.x;
                    acc[q][1]  += v[q] * w0.y;
                    acc[q][2]  += v[q] * w0.z;
                    acc[q][3]  += v[q] * w0.w;
                    acc[q][4]  += v[q] * w1.x;
                    acc[q][5]  += v[q] * w1.y;
                    acc[q][6]  += v[q] * w1.z;
                    acc[q][7]  += v[q] * w1.w;
                    acc[q][8]  += v[q] * w2.x;
                    acc[q][9]  += v[q] * w2.y;
                    acc[q][10] += v[q] * w2.z;
                    acc[q][11] += v[q] * w2.w;
                    acc[q][12] += v[q] * w3.x;
                    acc[q][13] += v[q] * w3.y;
                    acc[q][14] += v[q] * w3.z;
                    acc[q][15] += v[q] * w3.w;
                }
            }
        }
    }

#pragma unroll
    for (int oo = 0; oo < 16; ++oo) {
        int o = wbase + oo;
#pragma unroll
        for (int q = 0; q < 4; ++q)
            out[((size_t)(b * COUT + o) * HH + (y0 + q)) * WW + col] = acc[q][oo];
    }
}

extern "C" void kernel_launch(void* const* d_in, const int* in_sizes, int n_in,
                              void* d_out, int out_size, void* d_ws, size_t ws_size,
                              hipStream_t stream) {
    const float* x     = (const float*)d_in[0];
    const float* ow    = (const float*)d_in[1];
    const float* obias = (const float*)d_in[2];
    const float* wh    = (const float*)d_in[3];
    const float* wv    = (const float*)d_in[4];
    float* out = (float*)d_out;
    float* off = (float*)d_ws;   // 8*6*128*128 floats = 3.1 MB scratch

    offset_kernel<<<dim3(8 * 32), dim3(256), 0, stream>>>(x, ow, obias, off);
    // 512 blocks: b(8) x ytile(32, 4 rows) x xtile(2, 64 cols)
    main_kernel<<<dim3(8 * 32 * 2), dim3(256), 0, stream>>>(x, off, wh, wv, out);
}

// Round 3
// 257.281 us; speedup vs baseline: 1.2947x; 1.2947x over previous
//
#include <hip/hip_runtime.h>

#define HH 128
#define WW 128
#define HW (HH * WW)
#define CIN 64
#define COUT 64

// ws layout (bytes):
//   off : [0, 3145728)                 8*6*128*128 fp32
//   Wt  : [3145728, 3244032)           [2][3][64 c][64 o] fp32 (main weights, o-contiguous)
//   OWt : [3244032, 3260416)           [64 c][64 (t*6+j, pad)] fp32 (offset weights)
#define OFF_OFF 0
#define WT_OFF  3145728
#define OWT_OFF 3244032

// -------------------------------------------------------------------------
// Prep: transpose weights so that for fixed (k,c) the outputs are contiguous
// -> wave-uniform s_load_dwordx16 in the hot loops.
// -------------------------------------------------------------------------
__global__ __launch_bounds__(256) void prep_kernel(const float* __restrict__ ow,
                                                   const float* __restrict__ wh,
                                                   const float* __restrict__ wv,
                                                   float* __restrict__ Wt,
                                                   float* __restrict__ OWt) {
    int i = blockIdx.x * 256 + threadIdx.x;
    if (i < 2 * 3 * CIN * COUT) {
        int o  = i & 63;
        int c  = (i >> 6) & 63;
        int pk = i >> 12;            // ph*3+k
        int k  = pk % 3;
        const float* src = (pk < 3) ? wh : wv;   // wh (O,C,1,K) / wv (O,C,K,1) flatten same
        Wt[i] = src[(o * CIN + c) * 3 + k];
    } else {
        int m = i - 24576;
        if (m < CIN * 54) {
            int c  = m / 54;
            int r2 = m - c * 54;
            int t  = r2 / 6;
            int j  = r2 - t * 6;
            OWt[c * 64 + r2] = ow[(j * CIN + c) * 9 + t];
        }
    }
}

// -------------------------------------------------------------------------
// Offset conv: block = 4 rows x 64 cols (1 px/thread). Per 2-channel chunk:
// stage 6x66 x-tile in LDS (zero-padded, coalesced), weights via uniform
// s_load from OWt (scalar pipe, no LDS).
// -------------------------------------------------------------------------
__global__ __launch_bounds__(256) void offset_kernel(const float* __restrict__ x,
                                                     const float* __restrict__ OWt,
                                                     const float* __restrict__ obias,
                                                     float* __restrict__ off) {
    __shared__ float lt[2 * 6 * 66];   // 3.1 KB

    const int tid = threadIdx.x;
    const int blk = blockIdx.x;        // b(8) x yt(32) x xt(2)
    const int b   = blk >> 6;
    const int y0  = ((blk >> 1) & 31) << 2;
    const int x0  = (blk & 1) << 6;

    const int r   = tid >> 6;          // 0..3
    const int col = tid & 63;
    const int y   = y0 + r;
    const int xq  = x0 + col;

    const float* xb = x + (size_t)b * CIN * HW;

    float acc[6];
#pragma unroll
    for (int j = 0; j < 6; ++j) acc[j] = obias[j];

    for (int cc0 = 0; cc0 < CIN; cc0 += 2) {
        if (cc0) __syncthreads();      // protect previous chunk's reads
#pragma unroll
        for (int e = tid; e < 2 * 396; e += 256) {
            int cc  = e >= 396;
            int rem = e - cc * 396;
            int row = rem / 66;
            int cl  = rem - row * 66;
            int yy  = y0 - 1 + row;
            int xx  = x0 - 1 + cl;
            bool v  = (yy >= 0) && (yy < HH) && (xx >= 0) && (xx < WW);
            lt[e] = v ? xb[(size_t)(cc0 + cc) * HW + yy * WW + xx] : 0.f;
        }
        __syncthreads();

#pragma unroll
        for (int cc = 0; cc < 2; ++cc) {
            const float* wrow = OWt + (cc0 + cc) * 64;   // wave-uniform -> s_load
#pragma unroll
            for (int dy = 0; dy < 3; ++dy) {
#pragma unroll
                for (int dx = 0; dx < 3; ++dx) {
                    float v = lt[cc * 396 + (r + dy) * 66 + (col + dx)];
                    const float* w6 = wrow + (dy * 3 + dx) * 6;
#pragma unroll
                    for (int j = 0; j < 6; ++j) acc[j] += v * w6[j];
                }
            }
        }
    }
#pragma unroll
    for (int j = 0; j < 6; ++j)
        off[((size_t)(b * 6 + j) * HH + y) * WW + xq] = acc[j];
}

// -------------------------------------------------------------------------
// Main: per (phase,k): gather each pixel ONCE into LDS V[c][256 px] (32 KB
// half-chunks), then GEMM: thread = 16 outs x 4 contiguous px, V via one
// ds_read_b128 per c, weights via wave-uniform s_load_dwordx16 (scalar pipe).
// LDS read traffic: 1 b128 per 64 FMAs = 0.25 B/FMA (vs 4 B/FMA round 1).
// -------------------------------------------------------------------------
__global__ __launch_bounds__(256) void main_kernel(const float* __restrict__ x,
                                                   const float* __restrict__ off,
                                                   const float* __restrict__ Wt,
                                                   float* __restrict__ out) {
    __shared__ float V[32 * 256];      // 32 KB: [c-half][px]

    const int tid = threadIdx.x;
    const int blk = blockIdx.x;        // b(8) x yt(32) x xt(2)
    const int b   = blk >> 6;
    const int y0  = ((blk >> 1) & 31) << 2;
    const int x0  = (blk & 1) << 6;

    // staging mapping: px = tid
    const int ys = y0 + (tid >> 6);
    const int xs = x0 + (tid & 63);
    // compute mapping: px = 4*lane+q, outs = os..os+15
    const int lane = tid & 63;
    const int os   = __builtin_amdgcn_readfirstlane((tid >> 6) << 4);

    const float* xb   = x   + (size_t)b * CIN * HW;
    const float* offb = off + (size_t)b * 6 * HW;

    float4 acc[16];
#pragma unroll
    for (int oo = 0; oo < 16; ++oo) acc[oo] = make_float4(0.f, 0.f, 0.f, 0.f);

    for (int pk = 0; pk < 6; ++pk) {   // ph*3+k
        const int ph = pk / 3;
        const int k  = pk - ph * 3;

        // ---- per-pixel sample meta (computed once per tap) ----
        float o1 = offb[(pk * HH + ys) * WW + xs];
        float wA, wB;
        int idxA, idxB;
        if (ph == 0) {
            // horizontal: py = ys + off (frac), px = xs + k - 1 (int)
            float py  = (float)ys + o1;
            float y0f = floorf(py);
            float wy  = py - y0f;
            int   yi  = (int)y0f;
            bool v0 = (yi >= 0) && (yi <= HH - 1);
            bool v1 = (yi + 1 >= 0) && (yi + 1 <= HH - 1);
            int  px = xs + k - 1;
            bool pv = (px >= 0) && (px <= WW - 1);
            wA = (pv && v0) ? (1.f - wy) : 0.f;
            wB = (pv && v1) ? wy : 0.f;
            int ra = min(max(yi, 0), HH - 1);
            int rb = min(max(yi + 1, 0), HH - 1);
            int ca = min(max(px, 0), WW - 1);
            idxA = ra * WW + ca;
            idxB = rb * WW + ca;
        } else {
            // vertical: py = ys + k - 1 (int), px = xs + off (frac)
            float px  = (float)xs + o1;
            float x0f = floorf(px);
            float wx  = px - x0f;
            int   xi  = (int)x0f;
            bool v0 = (xi >= 0) && (xi <= WW - 1);
            bool v1 = (xi + 1 >= 0) && (xi + 1 <= WW - 1);
            int  py = ys + k - 1;
            bool pv = (py >= 0) && (py <= HH - 1);
            wA = (pv && v0) ? (1.f - wx) : 0.f;
            wB = (pv && v1) ? wx : 0.f;
            int ra = min(max(py, 0), HH - 1);
            int ca = min(max(xi, 0), WW - 1);
            int cb = min(max(xi + 1, 0), WW - 1);
            idxA = ra * WW + ca;
            idxB = ra * WW + cb;
        }

        for (int ch = 0; ch < CIN; ch += 32) {
            if (pk || ch) __syncthreads();   // protect previous chunk's reads
            // ---- stage: gather 32 channels for own pixel ----
            const float* xA = xb + (size_t)ch * HW + idxA;
            const float* xB = xb + (size_t)ch * HW + idxB;
#pragma unroll 4
            for (int c = 0; c < 32; ++c) {
                float va = xA[(size_t)c * HW];
                float vb = xB[(size_t)c * HW];
                V[c * 256 + tid] = wA * va + wB * vb;
            }
            __syncthreads();
            // ---- GEMM chunk ----
            const float* wbase = Wt + ((pk * CIN + ch) * COUT) + os;  // uniform
            for (int c = 0; c < 32; ++c) {
                const float4 v4 = *(const float4*)&V[c * 256 + (lane << 2)];
                const float* w = wbase + c * COUT;                    // uniform -> s_load
#pragma unroll
                for (int oo = 0; oo < 16; ++oo) {
                    float ws = w[oo];
                    acc[oo].x += ws * v4.x;
                    acc[oo].y += ws * v4.y;
                    acc[oo].z += ws * v4.z;
                    acc[oo].w += ws * v4.w;
                }
            }
        }
    }

    const int yo = y0 + (lane >> 4);
    const int xo = x0 + ((lane & 15) << 2);
#pragma unroll
    for (int oo = 0; oo < 16; ++oo) {
        float4* op = (float4*)&out[((size_t)(b * COUT + os + oo) * HH + yo) * WW + xo];
        *op = acc[oo];
    }
}

extern "C" void kernel_launch(void* const* d_in, const int* in_sizes, int n_in,
                              void* d_out, int out_size, void* d_ws, size_t ws_size,
                              hipStream_t stream) {
    const float* x     = (const float*)d_in[0];
    const float* ow    = (const float*)d_in[1];
    const float* obias = (const float*)d_in[2];
    const float* wh    = (const float*)d_in[3];
    const float* wv    = (const float*)d_in[4];
    float* out = (float*)d_out;

    char* ws   = (char*)d_ws;
    float* off = (float*)(ws + OFF_OFF);
    float* Wt  = (float*)(ws + WT_OFF);
    float* OWt = (float*)(ws + OWT_OFF);

    prep_kernel<<<dim3(110), dim3(256), 0, stream>>>(ow, wh, wv, Wt, OWt);
    offset_kernel<<<dim3(512), dim3(256), 0, stream>>>(x, OWt, obias, off);
    main_kernel<<<dim3(512), dim3(256), 0, stream>>>(x, off, Wt, out);
}

// Round 4
// 210.416 us; speedup vs baseline: 1.5831x; 1.2227x over previous
//
#include <hip/hip_runtime.h>

#define HH 128
#define WW 128
#define HW (HH * WW)
#define CIN 64
#define COUT 64

// ws layout (bytes):
//   off : [0, 3145728)            8*6*128*128 fp32
//   Bf  : [3145728, +49152)       MFMA B-fragments, bf16: [pk6][kc2][nt4][lane64][j8]
//   OWt : [3194880, +16384)       offset weights fp32 [c][t*6+j pad 64]
#define OFF_OFF 0
#define BF_OFF  3145728
#define OWT_OFF 3194880

typedef short bf16x8 __attribute__((ext_vector_type(8)));
typedef float f32x4 __attribute__((ext_vector_type(4)));

__device__ __forceinline__ unsigned short f2bf(float f) {
    union { float f; unsigned int u; } v; v.f = f;
    unsigned int r = v.u + 0x7FFFu + ((v.u >> 16) & 1u);   // RNE
    return (unsigned short)(r >> 16);
}

// -------------------------------------------------------------------------
// Prep: (1) main weights -> bf16 MFMA B-fragment order
//       (2) offset weights -> [c][t*6+j] rows for scalar-pipe loads
// -------------------------------------------------------------------------
__global__ __launch_bounds__(256) void prep_kernel(const float* __restrict__ ow,
                                                   const float* __restrict__ wh,
                                                   const float* __restrict__ wv,
                                                   unsigned short* __restrict__ Bf,
                                                   float* __restrict__ OWt) {
    int i = blockIdx.x * 256 + threadIdx.x;
    if (i < 24576) {
        int j    = i & 7;
        int lane = (i >> 3) & 63;
        int nt   = (i >> 9) & 3;
        int kc   = (i >> 11) & 1;
        int pk   = i >> 12;                    // ph*3+k
        int o = nt * 16 + (lane & 15);
        int c = kc * 32 + (lane >> 4) * 8 + j;
        int k = pk % 3;
        const float* src = (pk < 3) ? wh : wv; // both flatten as (O,C,3)
        Bf[i] = f2bf(src[(o * CIN + c) * 3 + k]);
    } else {
        int m = i - 24576;
        if (m < 4096) {
            int c  = m >> 6;
            int r2 = m & 63;
            if (r2 < 54) {
                int t = r2 / 6, j = r2 - t * 6;
                OWt[c * 64 + r2] = ow[(j * CIN + c) * 9 + t];
            }
        }
    }
}

// -------------------------------------------------------------------------
// Offset conv: 1024 blocks, tile = 2 rows x 64 cols. 8-channel chunks:
// stage 4x66 halo per channel (coalesced), thread = col x cquarter computes
// BOTH rows for 2 channels (rows shared: 12 LDS reads feed 2px x 9 taps).
// Weights via wave-uniform s_load (cp = wave id). Cross-wave partial-sum
// reduction through LDS at the end.
// -------------------------------------------------------------------------
__global__ __launch_bounds__(256) void offset_kernel(const float* __restrict__ x,
                                                     const float* __restrict__ OWt,
                                                     const float* __restrict__ obias,
                                                     float* __restrict__ off) {
    __shared__ float lt[8 * 4 * 66];      // 8448 B halo chunk
    __shared__ float red[4 * 2 * 6 * 64]; // 12 KB partial sums

    const int tid = threadIdx.x;
    const int blk = blockIdx.x;           // b(8) x yt(64) x xt(2)
    const int b   = blk >> 7;
    const int yt  = (blk & 127) >> 1;
    const int y0  = yt << 1;
    const int x0  = (blk & 1) << 6;

    const int col = tid & 63;
    const int cp  = tid >> 6;             // wave id = channel quarter

    const float* xb = x + (size_t)b * CIN * HW;

    float acc[2][6];
#pragma unroll
    for (int p = 0; p < 2; ++p)
#pragma unroll
        for (int j = 0; j < 6; ++j) acc[p][j] = 0.f;

    for (int cc0 = 0; cc0 < CIN; cc0 += 8) {
        if (cc0) __syncthreads();
        for (int e = tid; e < 8 * 264; e += 256) {
            int c   = e / 264;
            int rem = e - c * 264;
            int row = rem / 66;
            int cl  = rem - row * 66;
            int yy  = y0 - 1 + row;
            int xx  = x0 - 1 + cl;
            bool v  = (yy >= 0) && (yy < HH) && (xx >= 0) && (xx < WW);
            lt[e] = v ? xb[(size_t)(cc0 + c) * HW + yy * WW + xx] : 0.f;
        }
        __syncthreads();

#pragma unroll
        for (int i = 0; i < 2; ++i) {
            int cl = cp * 2 + i;
            const float* wrow = OWt + (cc0 + cl) * 64;   // wave-uniform -> s_load
            float rv[4][3];
#pragma unroll
            for (int row = 0; row < 4; ++row)
#pragma unroll
                for (int dx = 0; dx < 3; ++dx)
                    rv[row][dx] = lt[cl * 264 + row * 66 + col + dx];
#pragma unroll
            for (int dy = 0; dy < 3; ++dy)
#pragma unroll
                for (int dx = 0; dx < 3; ++dx) {
                    const float* w6 = wrow + (dy * 3 + dx) * 6;
#pragma unroll
                    for (int j = 0; j < 6; ++j) {
                        acc[0][j] += rv[dy][dx] * w6[j];
                        acc[1][j] += rv[dy + 1][dx] * w6[j];
                    }
                }
        }
    }

    // reduce 4 channel-quarters
#pragma unroll
    for (int p = 0; p < 2; ++p)
#pragma unroll
        for (int j = 0; j < 6; ++j)
            red[((cp * 2 + p) * 6 + j) * 64 + col] = acc[p][j];
    __syncthreads();

    for (int e = tid; e < 768; e += 256) {   // 2 rows x 6 j x 64 cols
        int p   = e / 384;
        int rem = e - p * 384;
        int j   = rem >> 6;
        int cl  = rem & 63;
        float s = obias[j];
#pragma unroll
        for (int q = 0; q < 4; ++q)
            s += red[((q * 2 + p) * 6 + j) * 64 + cl];
        off[((size_t)(b * 6 + j) * HH + (y0 + p)) * WW + (x0 + cl)] = s;
    }
}

// -------------------------------------------------------------------------
// Main: 1024 blocks, tile = 128 px (2 rows x 64 cols) x 64 outs.
// Per tap: gather+lerp each pixel once -> bf16 V[px][c] in LDS (row pad 72),
// then MFMA 16x16x32_bf16: wave w = m-tiles {2w,2w+1} x 4 n-tiles,
// K-loop = 2 chunks of 32 channels. B-frags from prep (L2-hot).
// -------------------------------------------------------------------------
__global__ __launch_bounds__(256) void main_kernel(const float* __restrict__ x,
                                                   const float* __restrict__ off,
                                                   const unsigned short* __restrict__ Bf,
                                                   float* __restrict__ out) {
    __shared__ unsigned short V[128 * 72];   // 18432 B, [px][c pad 72]

    const int tid  = threadIdx.x;
    const int lane = tid & 63;
    const int w    = tid >> 6;
    const int px   = tid & 127;              // staging pixel
    const int h    = tid >> 7;               // staging channel half

    const int blk = blockIdx.x;              // b(8) x yt(64) x xt(2)
    const int b   = blk >> 7;
    const int y0  = ((blk & 127) >> 1) << 1;
    const int x0  = (blk & 1) << 6;

    const int ys = y0 + (px >> 6);
    const int xs = x0 + (px & 63);

    const float* xb   = x   + (size_t)b * CIN * HW;
    const float* offb = off + (size_t)b * 6 * HW;

    f32x4 acc[2][4];
#pragma unroll
    for (int mt = 0; mt < 2; ++mt)
#pragma unroll
        for (int nt = 0; nt < 4; ++nt) acc[mt][nt] = (f32x4){0.f, 0.f, 0.f, 0.f};

    for (int pk = 0; pk < 6; ++pk) {
        const int ph = pk / 3;
        const int k  = pk - ph * 3;

        // ---- per-pixel sample meta ----
        float o1 = offb[(pk * HH + ys) * WW + xs];
        float wA, wB;
        int idxA, idxB;
        if (ph == 0) {
            float py  = (float)ys + o1;
            float y0f = floorf(py);
            float wy  = py - y0f;
            int   yi  = (int)y0f;
            bool v0 = (yi >= 0) && (yi <= HH - 1);
            bool v1 = (yi + 1 >= 0) && (yi + 1 <= HH - 1);
            int  pxx = xs + k - 1;
            bool pv  = (pxx >= 0) && (pxx <= WW - 1);
            wA = (pv && v0) ? (1.f - wy) : 0.f;
            wB = (pv && v1) ? wy : 0.f;
            int ra = min(max(yi, 0), HH - 1);
            int rb = min(max(yi + 1, 0), HH - 1);
            int ca = min(max(pxx, 0), WW - 1);
            idxA = ra * WW + ca;
            idxB = rb * WW + ca;
        } else {
            float pxf = (float)xs + o1;
            float x0f = floorf(pxf);
            float wx  = pxf - x0f;
            int   xi  = (int)x0f;
            bool v0 = (xi >= 0) && (xi <= WW - 1);
            bool v1 = (xi + 1 >= 0) && (xi + 1 <= WW - 1);
            int  py = ys + k - 1;
            bool pv = (py >= 0) && (py <= HH - 1);
            wA = (pv && v0) ? (1.f - wx) : 0.f;
            wB = (pv && v1) ? wx : 0.f;
            int ra = min(max(py, 0), HH - 1);
            int ca = min(max(xi, 0), WW - 1);
            int cb = min(max(xi + 1, 0), WW - 1);
            idxA = ra * WW + ca;
            idxB = ra * WW + cb;
        }

        if (pk) __syncthreads();             // protect previous tap's V reads
        // ---- stage: lerp 32 channels for own pixel, write bf16 ----
#pragma unroll
        for (int jb = 0; jb < 4; ++jb) {
            float va[8], vb[8];
#pragma unroll
            for (int t = 0; t < 8; ++t) {
                int c = 32 * h + jb * 8 + t;
                va[t] = xb[(size_t)c * HW + idxA];
                vb[t] = xb[(size_t)c * HW + idxB];
            }
            union { unsigned short us[8]; uint4 u4; } pkd;
#pragma unroll
            for (int t = 0; t < 8; ++t) pkd.us[t] = f2bf(wA * va[t] + wB * vb[t]);
            *(uint4*)&V[px * 72 + h * 32 + jb * 8] = pkd.u4;
        }
        __syncthreads();

        // ---- MFMA: 2 K-steps of 32 channels ----
#pragma unroll
        for (int kci = 0; kci < 2; ++kci) {
            bf16x8 afrag[2];
#pragma unroll
            for (int mt = 0; mt < 2; ++mt) {
                int mrow = (2 * w + mt) * 16 + (lane & 15);
                afrag[mt] = *(const bf16x8*)&V[mrow * 72 + kci * 32 + (lane >> 4) * 8];
            }
#pragma unroll
            for (int nt = 0; nt < 4; ++nt) {
                bf16x8 bfrag = *(const bf16x8*)&Bf[(((pk * 2 + kci) * 4 + nt) * 64 + lane) * 8];
#pragma unroll
                for (int mt = 0; mt < 2; ++mt)
                    acc[mt][nt] = __builtin_amdgcn_mfma_f32_16x16x32_bf16(
                        afrag[mt], bfrag, acc[mt][nt], 0, 0, 0);
            }
        }
    }

    // ---- epilogue: C layout col=lane&15 (o), row=quad*4+reg (px) ----
#pragma unroll
    for (int mt = 0; mt < 2; ++mt) {
        int pxb = (2 * w + mt) * 16 + (lane >> 4) * 4;
#pragma unroll
        for (int nt = 0; nt < 4; ++nt) {
            int o = nt * 16 + (lane & 15);
            f32x4 a = acc[mt][nt];
#pragma unroll
            for (int reg = 0; reg < 4; ++reg) {
                int pxr = pxb + reg;
                int yo  = y0 + (pxr >> 6);
                int xo  = x0 + (pxr & 63);
                out[((size_t)(b * COUT + o) * HH + yo) * WW + xo] = a[reg];
            }
        }
    }
}

extern "C" void kernel_launch(void* const* d_in, const int* in_sizes, int n_in,
                              void* d_out, int out_size, void* d_ws, size_t ws_size,
                              hipStream_t stream) {
    const float* x     = (const float*)d_in[0];
    const float* ow    = (const float*)d_in[1];
    const float* obias = (const float*)d_in[2];
    const float* wh    = (const float*)d_in[3];
    const float* wv    = (const float*)d_in[4];
    float* out = (float*)d_out;

    char* ws = (char*)d_ws;
    float* off = (float*)(ws + OFF_OFF);
    unsigned short* Bf = (unsigned short*)(ws + BF_OFF);
    float* OWt = (float*)(ws + OWT_OFF);

    prep_kernel<<<dim3(112), dim3(256), 0, stream>>>(ow, wh, wv, Bf, OWt);
    offset_kernel<<<dim3(1024), dim3(256), 0, stream>>>(x, OWt, obias, off);
    main_kernel<<<dim3(1024), dim3(256), 0, stream>>>(x, off, Bf, out);
}